// Round 10
// baseline (487.694 us; speedup 1.0000x reference)
//
#include <hip/hip_runtime.h>
#include <hip/hip_fp16.h>

// Fixed problem shape
#define TOK   64
#define INF   4096
#define OUTF  11008
#define NUMEL (OUTF * INF)        // 45088768
#define NSLC  (NUMEL / 64)        // 704512 64-element slices
#define NBLK  (OUTF / 16)         // 688 N-tiles
#define KSPL  4                   // GEMM K-split -> 2752 blocks, K=1024 each
#define OUTN  (TOK * OUTF)        // 704512 output elems

// Harness dtypes: fp16 arrays arrive as fp32; ints as int32; output fp32.
typedef __attribute__((ext_vector_type(8))) _Float16 half8;
typedef __attribute__((ext_vector_type(4))) _Float16 half4;
typedef __attribute__((ext_vector_type(4))) float floatx4;
typedef __attribute__((ext_vector_type(4), aligned(4))) int int4u;   // dword-aligned dwordx4
typedef __attribute__((ext_vector_type(4))) int int4a;               // 16B-aligned dwordx4

// ---------------------------------------------------------------------------
// Precompute (R8-verified form, seed dropped — R9 showed no C-reduction):
// (a) x fp32 -> fp16 (512 KB, L2-resident GEMM A),
// (b) per-64-slice meta[s] = {c0, outlier mask lo, mask hi, pad} (16 B).
// ---------------------------------------------------------------------------
__global__ __launch_bounds__(256) void precompute_kernel(
    const float* __restrict__ x, const int* __restrict__ fppos, int nf,
    _Float16* __restrict__ x16, int* __restrict__ meta) {
  const int t = blockIdx.x * 256 + threadIdx.x;
  if (t < (TOK * INF) / 4) {
    const floatx4 f = *(const floatx4*)&x[t * 4];
    half4 h;
    h[0] = (_Float16)f[0]; h[1] = (_Float16)f[1];
    h[2] = (_Float16)f[2]; h[3] = (_Float16)f[3];
    *(half4*)&x16[t * 4] = h;
  }
  if (t < NSLC) {
    const int target = t << 6;
    int lo = 0, hi = nf;
    while (lo < hi) {
      const int mid = (lo + hi) >> 1;
      if (fppos[mid] < target) lo = mid + 1; else hi = mid;
    }
    unsigned long long mask = 0ull;
    int j = lo;
    while (j < nf) {                 // mean 0.17 iters; P(>2) ~ 1e-4
      const int d = fppos[j] - target;
      if (d >= 64) break;
      mask |= 1ull << d;
      ++j;
    }
    int4a mv;
    mv[0] = lo;
    mv[1] = (int)(unsigned)(mask & 0xffffffffu);
    mv[2] = (int)(unsigned)(mask >> 32);
    mv[3] = 0;
    *(int4a*)&meta[t * 4] = mv;
  }
}

// ---------------------------------------------------------------------------
// dq_slot_meta (R3-verified verbatim): meta-driven dequant of one positioned
// 8-slot [p0, p0+8) -> half8. i0 = p0 - c0 - popc(mask below off); outlier
// values fpdat[c0+lt+rank]; i8 as two dword-aligned dwordx4; q-walk repair.
// ---------------------------------------------------------------------------
__device__ __forceinline__ half8 dq_slot_meta(
    const int p0, const int c0, const unsigned mlo, const unsigned mhi,
    const float s, const int* __restrict__ i8,
    const float* __restrict__ fpdat, const int n8) {
  const int off = p0 & 63;  // multiple of 8; 8-bit window never straddles
  const unsigned m8 = 0xffu & (off < 32 ? (mlo >> off) : (mhi >> (off - 32)));
  const unsigned bl = (off >= 32) ? mlo : (mlo & ((1u << off) - 1u));
  const unsigned bh = (off >= 32) ? (mhi & ((1u << (off - 32)) - 1u)) : 0u;
  const int lt = __popc(bl) + __popc(bh);
  const int i0 = p0 - c0 - lt;  // compacted index of position p0
  const int f  = (int)m8;

  float ov[8];
#pragma unroll
  for (int e = 0; e < 8; ++e) ov[e] = 0.f;
  if (f) {
    int fi = c0 + lt;
#pragma unroll
    for (int e = 0; e < 8; ++e) {
      if ((f >> e) & 1) { ov[e] = fpdat[fi]; ++fi; }
    }
  }

  half8 oh;
  if (i0 + 8 <= n8) {
    int l[8];
    *(int4u*)&l[0] = *(const int4u*)&i8[i0];      // global_load_dwordx4
    *(int4u*)&l[4] = *(const int4u*)&i8[i0 + 4];  // (dword-aligned OK)
    if (f == 0) {
#pragma unroll
      for (int e = 0; e < 8; ++e) oh[e] = (_Float16)((float)l[e] * s);
    } else {
      int q = 0;
#pragma unroll
      for (int e = 0; e < 8; ++e) {
        const int flg = (f >> e) & 1;
        int lv = l[0];
#pragma unroll
        for (int qq = 1; qq < 8; ++qq) lv = (q == qq) ? l[qq] : lv;
        oh[e] = flg ? (_Float16)ov[e] : (_Float16)((float)lv * s);
        q += 1 - flg;
      }
    }
  } else {
    // Array-tail path (last few global slots only): clamped scalar loads.
    int c = 0;
    const int m = n8 - 1;
#pragma unroll
    for (int e = 0; e < 8; ++e) {
      const int flg = (f >> e) & 1;
      int idx = i0 + e - c;
      idx = idx < 0 ? 0 : (idx > m ? m : idx);
      oh[e] = flg ? (_Float16)ov[e] : (_Float16)((float)i8[idx] * s);
      c += flg;
    }
  }
  return oh;
}

// ---------------------------------------------------------------------------
// Dequant v10: materialize W in MFMA-FRAGMENT-TILED layout
//   Wt[nt][kc][quad][ln][e]  (nt<688 N-tile, kc<128 K-chunk of 32, quad<4,
//   ln<16 row-in-tile, e<8)  — linear halves idx = ((nt*128+kc)*64 + q*16+r)*8.
// Wave = one (nt, kc) 16x32 tile per iteration, lane = (r = lane>>2, q =
// lane&3): reads are 4-lane 128 B row-runs (16 clean segments/instr), and
// the wave's 64 half8 WRITES are one fully CONTIGUOUS 1 KB block. No
// barriers, no LDS; 22016 waves of TLP hide all latency. Scale is
// wave-K-constant (128 K never straddles a 1024 quant block).
// ---------------------------------------------------------------------------
__global__ __launch_bounds__(256) void dequant_kernel(
    const int* __restrict__ i8, const float* __restrict__ fpdat,
    const float* __restrict__ scales, const int* __restrict__ meta,
    _Float16* __restrict__ Wt, const int n8) {
  const int tid  = threadIdx.x;
  const int wave = tid >> 6;
  const int lane = tid & 63;
  const int r    = lane >> 2;
  const int q    = lane & 3;
  const int nt   = blockIdx.x >> 3;
  const int kcg  = ((blockIdx.x & 7) << 4) + (wave << 2);  // wave's 4 kc's
  const int row  = (nt << 4) + r;
  const float s  = scales[row * 4 + (kcg >> 5)];  // const over the 4 kc's

#pragma unroll
  for (int j = 0; j < 4; ++j) {
    const int kc = kcg + j;
    const int p0 = (row << 12) + (kc << 5) + (q << 3);
    const int4a mv = *(const int4a*)&meta[(p0 >> 6) * 4];
    const half8 oh = dq_slot_meta(p0, mv[0], (unsigned)mv[1], (unsigned)mv[2],
                                  s, i8, fpdat, n8);
    *(half8*)&Wt[(size_t)((nt * 128 + kc) * 64 + q * 16 + r) * 8] = oh;
  }
}

// ---------------------------------------------------------------------------
// GEMM v10 — pure streaming from tiled Wt. Because lane = quad*16 + ln IS
// the fragment index, the B-load is Wt_base + lane*16B: one perfectly
// coalesced 1 KB wave-load per K-step, directly usable as the MFMA B
// operand (no LDS, no shuffles, no index math). Wt was written by the
// previous kernel -> L3-resident (90 MB < 256 MB) -> B reads mostly skip
// HBM. Block (nt,kq): wave w streams K [kq*1024+w*256, +256) in 8 steps of
// 32; A from L2-resident x16; epilogue LDS reduce + partial store (R5-R9
// verified) + reduce kernel.
// mfma_f32_16x16x32_f16: A/B frag idx=lane&15, k=quad*8+j; D row=quad*4+i,
// col=lane&15  [verified R1-R9, absmax 0.03125].
// ---------------------------------------------------------------------------
__global__ __launch_bounds__(256) void gemm_kernel(
    const _Float16* __restrict__ x16, const _Float16* __restrict__ Wt,
    float* __restrict__ part) {
  __shared__ float red[4 * 64 * 16];  // 16 KB, epilogue only

  const int tid  = threadIdx.x;
  const int wave = tid >> 6;
  const int lane = tid & 63;
  const int quad = lane >> 4;
  const int ln   = lane & 15;
  const int nt   = blockIdx.x >> 2;
  const int kq   = blockIdx.x & 3;
  const int n0   = nt << 4;
  const int kb   = kq * 1024 + wave * 256;        // wave's K base
  const int kc0  = kq * 32 + wave * 8;            // wave's first K-chunk

  const _Float16* ap = &x16[ln * INF + kb + quad * 8];
  const _Float16* bp = &Wt[((size_t)(nt * 128 + kc0) * 64 + lane) * 8];

  floatx4 acc0 = {0,0,0,0}, acc1 = {0,0,0,0}, acc2 = {0,0,0,0}, acc3 = {0,0,0,0};
#pragma unroll
  for (int st = 0; st < 8; ++st) {
    const half8 bh = *(const half8*)&bp[st * 512];   // coalesced 1KB/wave
    const half8 a0 = *(const half8*)&ap[st * 32];
    const half8 a1 = *(const half8*)&ap[16 * INF + st * 32];
    const half8 a2 = *(const half8*)&ap[32 * INF + st * 32];
    const half8 a3 = *(const half8*)&ap[48 * INF + st * 32];
    acc0 = __builtin_amdgcn_mfma_f32_16x16x32_f16(a0, bh, acc0, 0, 0, 0);
    acc1 = __builtin_amdgcn_mfma_f32_16x16x32_f16(a1, bh, acc1, 0, 0, 0);
    acc2 = __builtin_amdgcn_mfma_f32_16x16x32_f16(a2, bh, acc2, 0, 0, 0);
    acc3 = __builtin_amdgcn_mfma_f32_16x16x32_f16(a3, bh, acc3, 0, 0, 0);
  }

  // ---- Cross-wave reduce (only barriers in the kernel) ----
  const int mb = quad * 4;
#pragma unroll
  for (int i = 0; i < 4; ++i) red[wave * 1024 + (mb + i)      * 16 + ln] = acc0[i];
#pragma unroll
  for (int i = 0; i < 4; ++i) red[wave * 1024 + (16 + mb + i) * 16 + ln] = acc1[i];
#pragma unroll
  for (int i = 0; i < 4; ++i) red[wave * 1024 + (32 + mb + i) * 16 + ln] = acc2[i];
#pragma unroll
  for (int i = 0; i < 4; ++i) red[wave * 1024 + (48 + mb + i) * 16 + ln] = acc3[i];
  __syncthreads();

  // ---- Plain partial store ----
  float* pp = &part[(size_t)kq * OUTN];
#pragma unroll
  for (int c2 = 0; c2 < 4; ++c2) {
    const int cell = tid + c2 * 256;  // 1024 cells = 64 m x 16 n
    const int mm = cell >> 4, nn = cell & 15;
    pp[mm * OUTF + n0 + nn] =
        red[cell] + red[1024 + cell] + red[2048 + cell] + red[3072 + cell];
  }
}

// ---------------------------------------------------------------------------
// Reduce: out = sum_kq part[kq] + bias. 11.3 MB read + 2.8 MB write ~ 3 us.
// ---------------------------------------------------------------------------
__global__ __launch_bounds__(256) void reduce_kernel(
    const float* __restrict__ part, const float* __restrict__ bias,
    float* __restrict__ out) {
  const int t  = blockIdx.x * 256 + threadIdx.x;  // 688*256 = 176128 exact
  const int i4 = t * 4;
  floatx4 a = *(const floatx4*)&part[i4];
#pragma unroll
  for (int k = 1; k < KSPL; ++k) {
    const floatx4 b = *(const floatx4*)&part[(size_t)k * OUTN + i4];
    a[0] += b[0]; a[1] += b[1]; a[2] += b[2]; a[3] += b[3];
  }
  const int nn = i4 % OUTF;  // OUTF % 4 == 0: float4 never straddles rows
  const floatx4 bb = *(const floatx4*)&bias[nn];
  a[0] += bb[0]; a[1] += bb[1]; a[2] += bb[2]; a[3] += bb[3];
  *(floatx4*)&out[i4] = a;
}

// ---------------------------------------------------------------------------
// Inputs: 0 x(fp32) 1 int8_data(i32) 2 fp16_data(fp32) 3 scales(fp32)
// 4 bias(fp32) 5 int8_pos(UNUSED) 6 fp16_pos(i32) 7 block_idx(UNUSED)
// ws: x16 (512 KB) | meta (11.3 MB) | part (11.3 MB) | Wt (90.2 MB)
// ---------------------------------------------------------------------------
extern "C" void kernel_launch(void* const* d_in, const int* in_sizes, int n_in,
                              void* d_out, int out_size, void* d_ws,
                              size_t ws_size, hipStream_t stream) {
  const float* x      = (const float*)d_in[0];
  const int*   i8     = (const int*)d_in[1];
  const float* fpdat  = (const float*)d_in[2];
  const float* scales = (const float*)d_in[3];
  const float* bias   = (const float*)d_in[4];
  const int*   fppos  = (const int*)d_in[6];

  char* wsp = (char*)d_ws;
  _Float16* x16  = (_Float16*)wsp;
  int*      meta = (int*)(wsp + (size_t)TOK * INF * sizeof(_Float16));
  float*    part = (float*)(wsp + (size_t)TOK * INF * sizeof(_Float16)
                                + (size_t)NSLC * 16);
  _Float16* Wt   = (_Float16*)(wsp + (size_t)TOK * INF * sizeof(_Float16)
                                   + (size_t)NSLC * 16
                                   + (size_t)KSPL * OUTN * sizeof(float));
  float*    out  = (float*)d_out;

  const int n8 = in_sizes[1];
  const int nf = in_sizes[2];

  precompute_kernel<<<NSLC / 256, 256, 0, stream>>>(x, fppos, nf, x16, meta);
  dequant_kernel<<<NBLK * 8, 256, 0, stream>>>(i8, fpdat, scales, meta, Wt, n8);
  gemm_kernel<<<NBLK * KSPL, 256, 0, stream>>>(x16, Wt, part);
  reduce_kernel<<<OUTN / (4 * 256), 256, 0, stream>>>(part, bias, out);
}

// Round 11
// 435.180 us; speedup vs baseline: 1.1207x; 1.1207x over previous
//
#include <hip/hip_runtime.h>
#include <hip/hip_fp16.h>

// Fixed problem shape
#define TOK   64
#define INF   4096
#define OUTF  11008
#define NUMEL (OUTF * INF)        // 45088768
#define NSLC  (NUMEL / 64)        // 704512 64-element slices
#define NBLK  (OUTF / 16)         // 688 N-tiles
#define KSPL  8                   // K-split -> 5504 blocks, K=512 each
#define OUTN  (TOK * OUTF)        // 704512 output elems

// Harness dtypes: fp16 arrays arrive as fp32; ints as int32; output fp32.
typedef __attribute__((ext_vector_type(8))) _Float16 half8;
typedef __attribute__((ext_vector_type(4))) _Float16 half4;
typedef __attribute__((ext_vector_type(4))) float floatx4;
typedef __attribute__((ext_vector_type(4), aligned(4))) int int4u;   // dword-aligned dwordx4
typedef __attribute__((ext_vector_type(4))) int int4a;               // 16B-aligned dwordx4

// ---------------------------------------------------------------------------
// Precompute (R8-verified): (a) x fp32 -> fp16 (512 KB, L2-resident GEMM A),
// (b) per-64-slice meta[s] = {c0, outlier mask lo, mask hi, pad} (16 B).
// ---------------------------------------------------------------------------
__global__ __launch_bounds__(256) void precompute_kernel(
    const float* __restrict__ x, const int* __restrict__ fppos, int nf,
    _Float16* __restrict__ x16, int* __restrict__ meta) {
  const int t = blockIdx.x * 256 + threadIdx.x;
  if (t < (TOK * INF) / 4) {
    const floatx4 f = *(const floatx4*)&x[t * 4];
    half4 h;
    h[0] = (_Float16)f[0]; h[1] = (_Float16)f[1];
    h[2] = (_Float16)f[2]; h[3] = (_Float16)f[3];
    *(half4*)&x16[t * 4] = h;
  }
  if (t < NSLC) {
    const int target = t << 6;
    int lo = 0, hi = nf;
    while (lo < hi) {
      const int mid = (lo + hi) >> 1;
      if (fppos[mid] < target) lo = mid + 1; else hi = mid;
    }
    unsigned long long mask = 0ull;
    int j = lo;
    while (j < nf) {                 // mean 0.17 iters; P(>2) ~ 1e-4
      const int d = fppos[j] - target;
      if (d >= 64) break;
      mask |= 1ull << d;
      ++j;
    }
    int4a mv;
    mv[0] = lo;
    mv[1] = (int)(unsigned)(mask & 0xffffffffu);
    mv[2] = (int)(unsigned)(mask >> 32);
    mv[3] = 0;
    *(int4a*)&meta[t * 4] = mv;
  }
}

// ---------------------------------------------------------------------------
// meta_window1 (R3-R9 verified verbatim): compacted i8 index i0 of position
// p0 + 8-bit outlier window. off multiple of 8 -> never straddles halves.
// ---------------------------------------------------------------------------
__device__ __forceinline__ void meta_window1(const int p0, const int4a mv,
                                             int& i0, unsigned& m8) {
  const unsigned mlo = (unsigned)mv[1];
  const unsigned mhi = (unsigned)mv[2];
  const int off = p0 & 63;
  m8 = 0xffu & (off < 32 ? (mlo >> off) : (mhi >> (off - 32)));
  const unsigned bl = (off >= 32) ? mlo : (mlo & ((1u << off) - 1u));
  const unsigned bh = (off >= 32) ? (mhi & ((1u << (off - 32)) - 1u)) : 0u;
  i0 = p0 - mv[0] - (__popc(bl) + __popc(bh));
}

// ---------------------------------------------------------------------------
// finish_slot (R2-R9 verbatim): SLOW path only (>2 outliers in one 8-slot,
// ~1e-6 of slots; wave-uniformly skipped otherwise -> execz branch).
// ---------------------------------------------------------------------------
__device__ __forceinline__ half8 finish_slot(
    const unsigned m8, const int i0, const int p0, const float s,
    const int (&l)[8], const int* __restrict__ i8,
    const float* __restrict__ fpdat, const int n8) {
  const int f = (int)m8;
  float ov[8];
#pragma unroll
  for (int e = 0; e < 8; ++e) ov[e] = 0.f;
  if (f) {
    int fi = p0 - i0;  // c0 + (#outliers below p0)
#pragma unroll
    for (int e = 0; e < 8; ++e) {
      if ((f >> e) & 1) { ov[e] = fpdat[fi]; ++fi; }
    }
  }

  half8 oh;
  if (i0 + 8 <= n8) {
    if (f == 0) {
#pragma unroll
      for (int e = 0; e < 8; ++e) oh[e] = (_Float16)((float)l[e] * s);
    } else {
      int q = 0;
#pragma unroll
      for (int e = 0; e < 8; ++e) {
        const int flg = (f >> e) & 1;
        int lv = l[0];
#pragma unroll
        for (int qq = 1; qq < 8; ++qq) lv = (q == qq) ? l[qq] : lv;
        oh[e] = flg ? (_Float16)ov[e] : (_Float16)((float)lv * s);
        q += 1 - flg;
      }
    }
  } else {
    int c = 0;
    const int m = n8 - 1;
#pragma unroll
    for (int e = 0; e < 8; ++e) {
      const int flg = (f >> e) & 1;
      int idx = i0 + e - c;
      idx = idx < 0 ? 0 : (idx > m ? m : idx);
      oh[e] = flg ? (_Float16)ov[e] : (_Float16)((float)i8[idx] * s);
      c += flg;
    }
  }
  return oh;
}

// Per-chunk HBM prefetch bank (R8/R9-proven no-spill shape): i8 dwords +
// meta-derived indices + UNCONDITIONALLY prefetched outlier values.
struct Pre {
  int la[8], lb[8];          // i8 dwords for the lane's two B fragment slots
  int i0a, i0b;
  unsigned m8a, m8b;
  float va0, va1, vb0, vb1;  // outlier values rank 0,1 per slot (uncond)
};

// ---------------------------------------------------------------------------
// Fused GEMM v11 — FIFO-ordered full-prefetch prologue.
// R9 counters: 1.85 TB/s at occ 40% -> ~2.7 KB/CU in flight = one chunk's
// loads per wave; per-chunk serial meta->i8 HBM round trips dominate. v11:
// KSPL=8 (wave-K = 128 = 2 chunks) so the ENTIRE wave's HBM working set
// issues in the prologue in strict FIFO order: meta(2) -> wait -> window
// VALU -> A(chunk0, L2) -> i8+fpdat bank0 -> i8+fpdat bank1. fpdat loads
// are UNCONDITIONAL (clamped addr) so vmcnt counts stay static. Chunk0's
// consume then waits vmcnt(#bank1) — bank1 rides in flight across chunk0's
// compute; A(1) is the only mid-loop load (L2-resident x16). Zero barriers,
// zero LDS in the loop. 16 waves/CU each holding a full bank in flight.
// mfma_f32_16x16x32_f16 mapping + dequant numerics verified R1-R10.
// ---------------------------------------------------------------------------
__global__ __launch_bounds__(256, 4) void gemm_fused(
    const _Float16* __restrict__ x16, const int* __restrict__ i8,
    const float* __restrict__ fpdat, const float* __restrict__ scales,
    const int* __restrict__ meta, float* __restrict__ part,
    const int n8, const int nf) {
  __shared__ float red[4 * 64 * 16];  // 16 KB, epilogue only

  const int tid  = threadIdx.x;
  const int wave = tid >> 6;
  const int lane = tid & 63;
  const int quad = lane >> 4;
  const int ln   = lane & 15;
  const int nt   = blockIdx.x >> 3;
  const int kq   = blockIdx.x & 7;
  const int n0   = nt << 4;
  const int kbas = kq * 512 + wave * 128;   // this wave's K base (2 chunks)
  const int qoff = quad * 8;

  const int prow  = n0 + ln;
  const int pbase = prow * INF + kbas;          // lane's positioned row-K base
  const float s   = scales[prow * 4 + (kq >> 1)];  // wave-K inside one q-block

#define ISSUE(BNK, CC, MV)                                                   \
  do {                                                                       \
    const int p0a_ = pbase + (CC) * 64 + qoff;                               \
    meta_window1(p0a_, (MV), BNK.i0a, BNK.m8a);                              \
    meta_window1(p0a_ + 32, (MV), BNK.i0b, BNK.m8b);                         \
    if (BNK.i0a + 8 <= n8) {                                                 \
      *(int4u*)&BNK.la[0] = *(const int4u*)&i8[BNK.i0a];                     \
      *(int4u*)&BNK.la[4] = *(const int4u*)&i8[BNK.i0a + 4];                 \
    }                                                                        \
    if (BNK.i0b + 8 <= n8) {                                                 \
      *(int4u*)&BNK.lb[0] = *(const int4u*)&i8[BNK.i0b];                     \
      *(int4u*)&BNK.lb[4] = *(const int4u*)&i8[BNK.i0b + 4];                 \
    }                                                                        \
    /* UNCONDITIONAL outlier-value prefetch (clamped): static load count */  \
    {                                                                        \
      int fia_ = p0a_ - BNK.i0a;                                             \
      fia_ = fia_ < nf - 1 ? fia_ : nf - 1;                                  \
      BNK.va0 = fpdat[fia_];                                                 \
      BNK.va1 = fpdat[fia_ + 1 < nf ? fia_ + 1 : nf - 1];                    \
      int fib_ = p0a_ + 32 - BNK.i0b;                                        \
      fib_ = fib_ < nf - 1 ? fib_ : nf - 1;                                  \
      BNK.vb0 = fpdat[fib_];                                                 \
      BNK.vb1 = fpdat[fib_ + 1 < nf ? fib_ + 1 : nf - 1];                    \
    }                                                                        \
  } while (0)

// Fast register-only combine (R8-verified): <=2 outliers per slot use
// prefetched V0/V1 by rank; int values via the q-walk select chain.
#define FSLOT(OH, LARR, M8, I0, V0, V1)                                      \
  do {                                                                       \
    const int f_ = (int)(M8);                                                \
    if ((I0) + 8 <= n8) {                                                    \
      if (f_ == 0) {                                                         \
        _Pragma("unroll")                                                    \
        for (int e = 0; e < 8; ++e) OH[e] = (_Float16)((float)LARR[e] * s);  \
      } else {                                                               \
        int q_ = 0;                                                          \
        _Pragma("unroll")                                                    \
        for (int e = 0; e < 8; ++e) {                                        \
          const int flg = (f_ >> e) & 1;                                     \
          const int rank = __popc(f_ & ((1 << e) - 1));                      \
          const float fv = (rank == 0) ? (V0) : (V1);                        \
          int lv = LARR[0];                                                  \
          _Pragma("unroll")                                                  \
          for (int qq = 1; qq < 8; ++qq) lv = (q_ == qq) ? LARR[qq] : lv;    \
          OH[e] = flg ? (_Float16)fv : (_Float16)((float)lv * s);            \
          q_ += 1 - flg;                                                     \
        }                                                                    \
      }                                                                      \
    } else {                                                                 \
      int c_ = 0;                                                            \
      const int m_ = n8 - 1;                                                 \
      _Pragma("unroll")                                                      \
      for (int e = 0; e < 8; ++e) {                                          \
        const int flg = (f_ >> e) & 1;                                       \
        const int rank = __popc(f_ & ((1 << e) - 1));                        \
        const float fv = (rank == 0) ? (V0) : (V1);                          \
        int idx = (I0) + e - c_;                                             \
        idx = idx < 0 ? 0 : (idx > m_ ? m_ : idx);                           \
        OH[e] = flg ? (_Float16)fv : (_Float16)((float)i8[idx] * s);         \
        c_ += flg;                                                           \
      }                                                                      \
    }                                                                        \
  } while (0)

// A-fragment loads for chunk CC into A0..A7 (L2-resident x16).
#define LOADA(CC)                                                            \
  do {                                                                       \
    const _Float16* ap_ = &x16[ln * INF + kbas + (CC) * 64 + qoff];          \
    A0 = *(const half8*)&ap_[0];                                             \
    A1 = *(const half8*)&ap_[16 * INF];                                      \
    A2 = *(const half8*)&ap_[32 * INF];                                      \
    A3 = *(const half8*)&ap_[48 * INF];                                      \
    A4 = *(const half8*)&ap_[32];                                            \
    A5 = *(const half8*)&ap_[16 * INF + 32];                                 \
    A6 = *(const half8*)&ap_[32 * INF + 32];                                 \
    A7 = *(const half8*)&ap_[48 * INF + 32];                                 \
  } while (0)

#define FIN_MFMA(BNK, CC)                                                    \
  do {                                                                       \
    const int p0a_ = pbase + (CC) * 64 + qoff;                               \
    half8 b0, b1;                                                            \
    FSLOT(b0, BNK.la, BNK.m8a, BNK.i0a, BNK.va0, BNK.va1);                   \
    FSLOT(b1, BNK.lb, BNK.m8b, BNK.i0b, BNK.vb0, BNK.vb1);                   \
    if (__any(__popc((int)BNK.m8a) > 2 || __popc((int)BNK.m8b) > 2)) {       \
      if (__popc((int)BNK.m8a) > 2)                                          \
        b0 = finish_slot(BNK.m8a, BNK.i0a, p0a_, s, BNK.la, i8, fpdat, n8);  \
      if (__popc((int)BNK.m8b) > 2)                                          \
        b1 = finish_slot(BNK.m8b, BNK.i0b, p0a_ + 32, s, BNK.lb,             \
                         i8, fpdat, n8);                                     \
    }                                                                        \
    acc0 = __builtin_amdgcn_mfma_f32_16x16x32_f16(A0, b0, acc0, 0, 0, 0);    \
    acc1 = __builtin_amdgcn_mfma_f32_16x16x32_f16(A1, b0, acc1, 0, 0, 0);    \
    acc2 = __builtin_amdgcn_mfma_f32_16x16x32_f16(A2, b0, acc2, 0, 0, 0);    \
    acc3 = __builtin_amdgcn_mfma_f32_16x16x32_f16(A3, b0, acc3, 0, 0, 0);    \
    acc0 = __builtin_amdgcn_mfma_f32_16x16x32_f16(A4, b1, acc0, 0, 0, 0);    \
    acc1 = __builtin_amdgcn_mfma_f32_16x16x32_f16(A5, b1, acc1, 0, 0, 0);    \
    acc2 = __builtin_amdgcn_mfma_f32_16x16x32_f16(A6, b1, acc2, 0, 0, 0);    \
    acc3 = __builtin_amdgcn_mfma_f32_16x16x32_f16(A7, b1, acc3, 0, 0, 0);    \
  } while (0)

  // ---- Prologue: FIFO order = meta -> (wait) windows -> A(0) -> bank0 ->
  //      bank1. Everything HBM the wave needs is in flight before chunk 0.
  const int4a mz0 = *(const int4a*)&meta[(pbase >> 6) * 4];
  const int4a mz1 = *(const int4a*)&meta[((pbase + 64) >> 6) * 4];
  half8 A0, A1, A2, A3, A4, A5, A6, A7;
  LOADA(0);
  Pre pA, pB;
  ISSUE(pA, 0, mz0);
  ISSUE(pB, 1, mz1);

  floatx4 acc0 = {0,0,0,0}, acc1 = {0,0,0,0}, acc2 = {0,0,0,0}, acc3 = {0,0,0,0};

  // ---- Chunk 0: waits vmcnt(#bank1) — bank1 stays in flight underneath ----
  FIN_MFMA(pA, 0);
  // ---- A(1): only mid-loop load (L2) ----
  LOADA(1);
  // ---- Chunk 1: bank1 has been in flight across all of chunk 0 ----
  FIN_MFMA(pB, 1);

#undef ISSUE
#undef FSLOT
#undef LOADA
#undef FIN_MFMA

  // ---- Epilogue: cross-wave reduce (only barriers in the kernel) ----
  const int mb = quad * 4;
#pragma unroll
  for (int i = 0; i < 4; ++i) red[wave * 1024 + (mb + i)      * 16 + ln] = acc0[i];
#pragma unroll
  for (int i = 0; i < 4; ++i) red[wave * 1024 + (16 + mb + i) * 16 + ln] = acc1[i];
#pragma unroll
  for (int i = 0; i < 4; ++i) red[wave * 1024 + (32 + mb + i) * 16 + ln] = acc2[i];
#pragma unroll
  for (int i = 0; i < 4; ++i) red[wave * 1024 + (48 + mb + i) * 16 + ln] = acc3[i];
  __syncthreads();

  // ---- Plain partial store ----
  float* pp = &part[(size_t)kq * OUTN];
#pragma unroll
  for (int c2 = 0; c2 < 4; ++c2) {
    const int cell = tid + c2 * 256;  // 1024 cells = 64 m x 16 n
    const int mm = cell >> 4, nn = cell & 15;
    pp[mm * OUTF + n0 + nn] =
        red[cell] + red[1024 + cell] + red[2048 + cell] + red[3072 + cell];
  }
}

// ---------------------------------------------------------------------------
// Reduce: out = sum_kq part[kq] + bias. 22.5 MB read + 2.8 MB write ~ 5 us.
// ---------------------------------------------------------------------------
__global__ __launch_bounds__(256) void reduce_kernel(
    const float* __restrict__ part, const float* __restrict__ bias,
    float* __restrict__ out) {
  const int t  = blockIdx.x * 256 + threadIdx.x;  // 688*256 = 176128 exact
  const int i4 = t * 4;
  floatx4 a = *(const floatx4*)&part[i4];
#pragma unroll
  for (int k = 1; k < KSPL; ++k) {
    const floatx4 b = *(const floatx4*)&part[(size_t)k * OUTN + i4];
    a[0] += b[0]; a[1] += b[1]; a[2] += b[2]; a[3] += b[3];
  }
  const int nn = i4 % OUTF;  // OUTF % 4 == 0: float4 never straddles rows
  const floatx4 bb = *(const floatx4*)&bias[nn];
  a[0] += bb[0]; a[1] += bb[1]; a[2] += bb[2]; a[3] += bb[3];
  *(floatx4*)&out[i4] = a;
}

// ---------------------------------------------------------------------------
// Inputs: 0 x(fp32) 1 int8_data(i32) 2 fp16_data(fp32) 3 scales(fp32)
// 4 bias(fp32) 5 int8_pos(UNUSED) 6 fp16_pos(i32) 7 block_idx(UNUSED)
// ws: x16 (512 KB) | meta (11.3 MB) | part (22.5 MB)
// ---------------------------------------------------------------------------
extern "C" void kernel_launch(void* const* d_in, const int* in_sizes, int n_in,
                              void* d_out, int out_size, void* d_ws,
                              size_t ws_size, hipStream_t stream) {
  const float* x      = (const float*)d_in[0];
  const int*   i8     = (const int*)d_in[1];
  const float* fpdat  = (const float*)d_in[2];
  const float* scales = (const float*)d_in[3];
  const float* bias   = (const float*)d_in[4];
  const int*   fppos  = (const int*)d_in[6];

  char* wsp = (char*)d_ws;
  _Float16* x16  = (_Float16*)wsp;
  int*      meta = (int*)(wsp + (size_t)TOK * INF * sizeof(_Float16));
  float*    part = (float*)(wsp + (size_t)TOK * INF * sizeof(_Float16)
                                + (size_t)NSLC * 16);
  float*    out  = (float*)d_out;

  const int n8 = in_sizes[1];
  const int nf = in_sizes[2];

  precompute_kernel<<<NSLC / 256, 256, 0, stream>>>(x, fppos, nf, x16, meta);
  gemm_fused<<<NBLK * KSPL, 256, 0, stream>>>(x16, i8, fpdat, scales, meta,
                                              part, n8, nf);
  reduce_kernel<<<OUTN / (4 * 256), 256, 0, stream>>>(part, bias, out);
}